// Round 11
// baseline (482.514 us; speedup 1.0000x reference)
//
#include <hip/hip_runtime.h>
#include <hip/hip_bf16.h>

// RGCN 2-layer encoder. N=50000, R=16, B=8, Dim=128, E=625000.
// fp32 in/out (runtime-detected), bf16 MFMA internals.
//
// R26: barrier-free fusegemm. Four schedules (R21 2-phase, R22 3-deep,
// R24 32-row, R25 seg-major) all pinned at ~54us with all pipes idle ->
// the shared element is per-segment vmcnt(0)+2x s_barrier lockstep across
// the block's 4 waves, with only 3.05 blocks/CU (grid-capped). Now: NO LDS
// A-tile, NO main-loop barriers. A-fragments load directly global->VGPR
// (lane l: contiguous 16B at row=mt*16+(l&15), k=kk4*32+(l>>4)*8; 64B/row
// coalescing). A read 4x from L2 (~460MB L2-side, well under 34.5TB/s) in
// exchange for 12 fully independent wave streams per CU. One syncthreads
// before the epilogue publishes the dtype flag (fixes a formal race too).
//
// Pipeline per layer: wallT[b][o][k]=bases[b]^T (slot8=selfw^T) + coefw fp32;
// agg2: wave-per-node CSR scan -> Gall[b][n][o] (basis space, 102MB);
// fusegemm: out[n][o] = [G(n) | x[n]] @ wallT (K=1152), epilogue LN+ReLU.

static constexpr int kDim = 128;
static constexpr int kRel = 16;
static constexpr int kBas = 8;
static constexpr int kSeg = kBas + 1;   // 8 bases + self

typedef __attribute__((ext_vector_type(8))) short bf16x8;
typedef __attribute__((ext_vector_type(4))) float f32x4;

static __device__ __forceinline__ float bf2f_rg(unsigned short h) {
    return __uint_as_float(((unsigned)h) << 16);
}
static __device__ __forceinline__ unsigned short f2bf_rg(float f) {
    unsigned u = __float_as_uint(f);
    u = u + 0x7fffu + ((u >> 16) & 1u);   // round-to-nearest-even
    return (unsigned short)(u >> 16);
}

// dtype flag from emb's first 128 halves (call with one full wave, tid<64):
// any bf16-decoded exponent >= 0x86 (|v|>=128/inf/nan) => input is fp32
static __device__ __forceinline__ int flag_from(const unsigned short* x, int lane) {
    unsigned e0 = ((unsigned)x[lane] >> 7) & 0xFFu;
    unsigned e1 = ((unsigned)x[lane + 64] >> 7) & 0xFFu;
    int bad = (e0 >= 0x86u) || (e1 >= 0x86u);
    return (__ballot(bad) != 0ull) ? 1 : 0;
}

// template-named kernel: sentinel stub (d_out fully overwritten by pipeline)
__global__ void RGCNEncoder_89962384982025_kernel(unsigned* p, int n) {
    int i = blockIdx.x * 256 + threadIdx.x;
    if (i < n) p[i] = 0x3F803F80u;
}

// convert emb (fp32 or bf16, flag derived inline) -> bf16 xin
__global__ void cvt_rg(const void* xraw, unsigned short* xout, int n) {
    __shared__ int fsh;
    if (threadIdx.x < 64) {
        int fl = flag_from((const unsigned short*)xraw, threadIdx.x);
        if (threadIdx.x == 0) fsh = fl;
    }
    __syncthreads();
    int f = fsh;
    int i = blockIdx.x * 256 + threadIdx.x;
    if (i >= n) return;
    if (f)
        xout[i] = f2bf_rg(((const float*)xraw)[i]);
    else
        xout[i] = ((const unsigned short*)xraw)[i];
}

__global__ void zero_rg(int* p, int n) {
    int i = blockIdx.x * 256 + threadIdx.x;
    if (i < n) p[i] = 0;
}

__global__ void count_rg(const int* ei, const int* et, int* cnt, int E) {
    int e = blockIdx.x * 256 + threadIdx.x;
    if (e < E) atomicAdd(&cnt[ei[e] * kRel + et[e]], 1);
}

// hierarchical scan, in place on rowptr (saves the incl buffer)
__global__ void scanA_rg(const int* cnt, int* rowptr, int* bsum, int n) {
    __shared__ int sh[256];
    int tid = threadIdx.x;
    int i = blockIdx.x * 256 + tid;
    int v = (i < n) ? cnt[i] : 0;
    sh[tid] = v;
    __syncthreads();
    for (int off = 1; off < 256; off <<= 1) {
        int t = (tid >= off) ? sh[tid - off] : 0;
        __syncthreads();
        sh[tid] += t;
        __syncthreads();
    }
    if (i < n) rowptr[i + 1] = sh[tid];
    if (tid == 255) bsum[blockIdx.x] = sh[255];
}
__global__ void scanB_rg(int* bsum, int nb) {
    __shared__ int partial[256];
    int tid = threadIdx.x;
    int chunk = (nb + 255) / 256;
    int s0 = tid * chunk;
    int s1 = min(s0 + chunk, nb);
    int sum = 0;
    for (int i = s0; i < s1; ++i) sum += bsum[i];
    partial[tid] = sum;
    __syncthreads();
    for (int off = 1; off < 256; off <<= 1) {
        int t = (tid >= off) ? partial[tid - off] : 0;
        __syncthreads();
        partial[tid] += t;
        __syncthreads();
    }
    int run = (tid == 0) ? 0 : partial[tid - 1];
    for (int i = s0; i < s1; ++i) { int v = bsum[i]; bsum[i] = run; run += v; }
}
__global__ void scanC_rg(int* rowptr, const int* bsum, int n) {
    int i = blockIdx.x * 256 + threadIdx.x;
    if (i < n) rowptr[i + 1] += bsum[blockIdx.x];
    if (i == 0) rowptr[0] = 0;
}

// fill: pcols entry packs col | rel<<26 (col < 2^26)
__global__ void fill_rg(const int* ei, const int* et, const int* rowptr,
                        int* cnt, int* pcols, int E) {
    int e = blockIdx.x * 256 + threadIdx.x;
    if (e < E) {
        int rel = et[e];
        int key = ei[e] * kRel + rel;
        int old = atomicSub(&cnt[key], 1);
        pcols[rowptr[key] + old - 1] = ei[E + e] | (rel << 26);
    }
}

// wallT[b][o][k] = bases[b][k][o] for b<8; slot 8 = selfw^T.
// Also stages coef decoded to fp32 (coefw[16][8]) for agg2's LDS mix table.
__global__ void wall_rg(const void* bases, const void* coef, const void* selfw,
                        const unsigned short* emb, unsigned short* wallT,
                        float* coefw) {
    __shared__ int fsh;
    if (threadIdx.x < 64) {
        int fl = flag_from(emb, threadIdx.x);
        if (threadIdx.x == 0) fsh = fl;
    }
    __syncthreads();
    int f = fsh;
    int idx = blockIdx.x * 256 + threadIdx.x;   // b*16384 + o*128 + k
    int b = idx >> 14;
    int o = (idx >> 7) & 127;
    int k = idx & 127;
    if (blockIdx.x == 0 && threadIdx.x < kRel * kBas) {
        coefw[threadIdx.x] = f ? ((const float*)coef)[threadIdx.x]
                               : bf2f_rg(((const unsigned short*)coef)[threadIdx.x]);
    }
    if (b < kBas) {
        float bv = f ? ((const float*)bases)[b * 16384 + k * 128 + o]
                     : bf2f_rg(((const unsigned short*)bases)[b * 16384 + k * 128 + o]);
        wallT[idx] = f2bf_rg(bv);
    } else {
        float sv = f ? ((const float*)selfw)[k * 128 + o]
                     : bf2f_rg(((const unsigned short*)selfw)[k * 128 + o]);
        wallT[idx] = f2bf_rg(sv);
    }
}

// aggregate-first in basis space: Gall[b][n][o] = sum_r coefw[r][b] *
// mean over r-bucket edges of x[col][o]. Wave per node (4 waves/block).
// Depth-4 batched gather: 4 readlanes + 4 independent loads in flight,
// then bucket-transition logic on the returned values (latency overlap).
// Writes: per b one contiguous 256B chunk at plane offset b*N*256.
__global__ __launch_bounds__(256) void agg2_rg(const int* rowptr2, const int* pcols,
                                               const unsigned short* xsrc,
                                               const float* coefw,
                                               unsigned short* Gall, int N) {
    __shared__ float csh[kRel * kBas];
    if (threadIdx.x < kRel * kBas) csh[threadIdx.x] = coefw[threadIdx.x];
    __syncthreads();
    int wv = threadIdx.x >> 6;
    int lane = threadIdx.x & 63;
    int n = blockIdx.x * 4 + wv;
    if (n >= N) return;
    const int s = rowptr2[n * kRel];          // wave-uniform -> scalar load
    const int e = rowptr2[n * kRel + kRel];
    const unsigned short* xl = xsrc + 2 * lane;
    float g0[kBas], g1[kBas];
#pragma unroll
    for (int b = 0; b < kBas; ++b) { g0[b] = 0.f; g1[b] = 0.f; }
    float s0 = 0.f, s1 = 0.f;
    int cur = -1, cnt = 0;
    auto flush = [&]() {
        float w = __builtin_amdgcn_rcpf((float)cnt);
        float t0 = s0 * w, t1 = s1 * w;
        const float* cr = csh + cur * kBas;
#pragma unroll
        for (int b = 0; b < kBas; ++b) {
            float c = cr[b];                  // broadcast ds_read
            g0[b] += c * t0;
            g1[b] += c * t1;
        }
        s0 = 0.f; s1 = 0.f; cnt = 0;
    };
    for (int base = s; base < e; base += 64) {
        int m = e - base;
        if (m > 64) m = 64;
        int pk = 0;
        if (base + lane < e) pk = pcols[base + lane];
        int i = 0;
        for (; i + 4 <= m; i += 4) {
            // issue 4 independent gathers back-to-back (4 in flight)
            int v0 = __builtin_amdgcn_readlane(pk, i);
            int v1 = __builtin_amdgcn_readlane(pk, i + 1);
            int v2 = __builtin_amdgcn_readlane(pk, i + 2);
            int v3 = __builtin_amdgcn_readlane(pk, i + 3);
            unsigned u0 = *(const unsigned*)(xl + (size_t)(v0 & 0x03FFFFFF) * 128);
            unsigned u1 = *(const unsigned*)(xl + (size_t)(v1 & 0x03FFFFFF) * 128);
            unsigned u2 = *(const unsigned*)(xl + (size_t)(v2 & 0x03FFFFFF) * 128);
            unsigned u3 = *(const unsigned*)(xl + (size_t)(v3 & 0x03FFFFFF) * 128);
            int r0 = (int)((unsigned)v0 >> 26);
            int r1 = (int)((unsigned)v1 >> 26);
            int r2 = (int)((unsigned)v2 >> 26);
            int r3 = (int)((unsigned)v3 >> 26);
            if (r0 != cur) { if (cnt) flush(); cur = r0; }
            s0 += __uint_as_float(u0 << 16); s1 += __uint_as_float(u0 & 0xffff0000u); ++cnt;
            if (r1 != cur) { flush(); cur = r1; }
            s0 += __uint_as_float(u1 << 16); s1 += __uint_as_float(u1 & 0xffff0000u); ++cnt;
            if (r2 != cur) { flush(); cur = r2; }
            s0 += __uint_as_float(u2 << 16); s1 += __uint_as_float(u2 & 0xffff0000u); ++cnt;
            if (r3 != cur) { flush(); cur = r3; }
            s0 += __uint_as_float(u3 << 16); s1 += __uint_as_float(u3 & 0xffff0000u); ++cnt;
        }
        for (; i < m; ++i) {
            int v = __builtin_amdgcn_readlane(pk, i);
            unsigned u = *(const unsigned*)(xl + (size_t)(v & 0x03FFFFFF) * 128);
            int rel = (int)((unsigned)v >> 26);
            if (rel != cur) { if (cnt) flush(); cur = rel; }
            s0 += __uint_as_float(u << 16);
            s1 += __uint_as_float(u & 0xffff0000u);
            ++cnt;
        }
    }
    if (cnt) flush();
    unsigned short* grow = Gall + (size_t)n * 128 + 2 * lane;
    const size_t plane = (size_t)N * 128;
#pragma unroll
    for (int b = 0; b < kBas; ++b) {
        unsigned outp = (unsigned)f2bf_rg(g0[b]) | ((unsigned)f2bf_rg(g1[b]) << 16);
        *(unsigned*)(grow + (size_t)b * plane) = outp;
    }
}

// fused GEMM: out[n][o] = [G(n) (K=1024) | x[n] (K=128)] @ wallT[seg][o][k]
// + bias, then LayerNorm + ReLU in-epilogue. 64-row C-tile, 4 waves each
// owning a 64x32 column slice (16x16x32 bf16 MFMA; C map m89/m91:
// col=lane&15, row=(lane>>4)*4+reg). NO LDS staging, NO main-loop barriers:
// A-fragments load directly global->VGPR (lane: 16B contiguous at
// row*256 + kk4*64 + lq*16 within the segment plane). Waves fully
// independent until the LN epilogue.
__global__ __launch_bounds__(256, 3) void fusegemm_rg(const unsigned short* Gall,
                                                      const unsigned short* x,
                                                      const unsigned short* wallT,
                                                      const void* bias, const void* gw,
                                                      const void* bw,
                                                      const unsigned short* emb,
                                                      unsigned short* out_b, float* out_f,
                                                      int ofp32, int M) {
    __shared__ float pS[64][5];
    __shared__ float pQ[64][5];
    __shared__ float mrs[64][2];
    __shared__ int fsh;
    const int m0 = blockIdx.x * 64;
    const int tid = threadIdx.x;
    const int wave = tid >> 6;
    const int lane = tid & 63;
    const int wn = wave * 32;
    const int lrow = lane & 15;
    const int lq = lane >> 4;
    if (tid < 64) {
        int fl = flag_from(emb, tid);
        if (tid == 0) fsh = fl;
    }

    // this lane's 4 A-row addresses (clamped), shared across segments
    size_t arow[4];
#pragma unroll
    for (int mt = 0; mt < 4; ++mt) {
        int gr = m0 + mt * 16 + lrow;
        if (gr > M - 1) gr = M - 1;
        arow[mt] = (size_t)gr * 128 + lq * 8;
    }

    f32x4 acc[4][2] = {};
#pragma unroll
    for (int seg = 0; seg < kSeg; ++seg) {
        const unsigned short* Aseg = (seg < kBas)
            ? Gall + (size_t)seg * (size_t)M * 128
            : x;
        const unsigned short* Bsrc = wallT + (size_t)seg * 16384;
        bf16x8 b[4][2];
#pragma unroll
        for (int kk4 = 0; kk4 < 4; ++kk4)
#pragma unroll
            for (int nt = 0; nt < 2; ++nt)
                b[kk4][nt] = *(const bf16x8*)(Bsrc + (size_t)(wn + nt * 16 + lrow) * 128
                                              + kk4 * 32 + lq * 8);
        bf16x8 a[4][4];
#pragma unroll
        for (int kk4 = 0; kk4 < 4; ++kk4)
#pragma unroll
            for (int mt = 0; mt < 4; ++mt)
                a[kk4][mt] = *(const bf16x8*)(Aseg + arow[mt] + kk4 * 32);
#pragma unroll
        for (int kk4 = 0; kk4 < 4; ++kk4)
#pragma unroll
            for (int mt = 0; mt < 4; ++mt)
#pragma unroll
                for (int nt = 0; nt < 2; ++nt)
                    acc[mt][nt] = __builtin_amdgcn_mfma_f32_16x16x32_bf16(
                        a[kk4][mt], b[kk4][nt], acc[mt][nt], 0, 0, 0);
    }
    __syncthreads();   // publish fsh; align waves for epilogue LDS use

    // epilogue: +bias, row mean/var across 128 cols (4 waves x 32 cols), LN+ReLU
    const int f = fsh;
    float bv[2], gv[2], betav[2];
#pragma unroll
    for (int nt = 0; nt < 2; ++nt) {
        int gc = wn + nt * 16 + lrow;
        if (f) {
            bv[nt] = ((const float*)bias)[gc];
            gv[nt] = ((const float*)gw)[gc];
            betav[nt] = ((const float*)bw)[gc];
        } else {
            bv[nt] = bf2f_rg(((const unsigned short*)bias)[gc]);
            gv[nt] = bf2f_rg(((const unsigned short*)gw)[gc]);
            betav[nt] = bf2f_rg(((const unsigned short*)bw)[gc]);
        }
    }
#pragma unroll
    for (int mt = 0; mt < 4; ++mt)
#pragma unroll
        for (int i = 0; i < 4; ++i) {
            float sv = 0.f, qv = 0.f;
#pragma unroll
            for (int nt = 0; nt < 2; ++nt) {
                float v = acc[mt][nt][i] + bv[nt];
                acc[mt][nt][i] = v;
                sv += v;
                qv += v * v;
            }
            for (int o = 1; o < 16; o <<= 1) {
                sv += __shfl_xor(sv, o);
                qv += __shfl_xor(qv, o);
            }
            if (lrow == 0) {
                int row = mt * 16 + lq * 4 + i;
                pS[row][wave] = sv;
                pQ[row][wave] = qv;
            }
        }
    __syncthreads();
    if (tid < 64) {
        float s4 = pS[tid][0] + pS[tid][1] + pS[tid][2] + pS[tid][3];
        float q4 = pQ[tid][0] + pQ[tid][1] + pQ[tid][2] + pQ[tid][3];
        float mean = s4 * (1.0f / 128.0f);
        float var = q4 * (1.0f / 128.0f) - mean * mean;
        mrs[tid][0] = mean;
        mrs[tid][1] = rsqrtf(var + 1e-5f);
    }
    __syncthreads();
#pragma unroll
    for (int mt = 0; mt < 4; ++mt)
#pragma unroll
        for (int i = 0; i < 4; ++i) {
            int row = mt * 16 + lq * 4 + i;
            int gr = m0 + row;
            if (gr < M) {
                float mean = mrs[row][0];
                float rs = mrs[row][1];
#pragma unroll
                for (int nt = 0; nt < 2; ++nt) {
                    int gc = wn + nt * 16 + lrow;
                    float o = fmaxf((acc[mt][nt][i] - mean) * rs * gv[nt] + betav[nt], 0.f);
                    if (ofp32)
                        out_f[(size_t)gr * 128 + gc] = o;
                    else
                        out_b[(size_t)gr * 128 + gc] = f2bf_rg(o);
                }
            }
        }
}

extern "C" void kernel_launch(void* const* d_in, const int* in_sizes, int n_in,
                              void* d_out, int out_size, void* d_ws, size_t ws_size,
                              hipStream_t stream) {
    const int* ei = (const int*)d_in[0];            // [2,E] int32
    const int* et = (const int*)d_in[1];            // [E] int32
    const void* emb    = d_in[2];
    const void* bases1 = d_in[3];
    const void* coef1  = d_in[4];
    const void* selfw1 = d_in[5];
    const void* bias1  = d_in[6];
    const void* g1     = d_in[7];
    const void* b1     = d_in[8];
    const void* bases2 = d_in[9];
    const void* coef2  = d_in[10];
    const void* selfw2 = d_in[11];
    const void* bias2  = d_in[12];
    const void* g2     = d_in[13];
    const void* b2     = d_in[14];

    const int E = in_sizes[1];
    const int N = out_size / kDim;
    const int n16 = N * kRel;
    const int nsb = (n16 + 255) / 256;

    // workspace (256B-aligned). Gall = [8][N][128] bf16 (102.4MB, seg-major).
    char* ws = (char*)d_ws;
    size_t off = 0;
    float* coefw = (float*)(ws + off); off += 512;
    int* rowptr2 = (int*)(ws + off); off += (((size_t)n16 + 1) * 4 + 255) & ~(size_t)255;
    int* cnt     = (int*)(ws + off); off += ((size_t)n16 * 4 + 255) & ~(size_t)255;
    int* bsum    = (int*)(ws + off); off += ((size_t)nsb * 4 + 255) & ~(size_t)255;
    int* pcols   = (int*)(ws + off); off += ((size_t)E * 4 + 255) & ~(size_t)255;
    unsigned short* wallT = (unsigned short*)(ws + off);
    off += ((size_t)kSeg * 16384 * 2 + 255) & ~(size_t)255;
    unsigned short* xin  = (unsigned short*)(ws + off);
    off += ((size_t)N * 128 * 2 + 255) & ~(size_t)255;
    unsigned short* xmid = (unsigned short*)(ws + off);
    off += ((size_t)N * 128 * 2 + 255) & ~(size_t)255;
    unsigned short* Gall = (unsigned short*)(ws + off);
    (void)n_in; (void)ws_size;

    const int eblk = (E + 255) / 256;
    const int mblk64 = (N + 63) / 64;
    const int ablk = (N + 3) / 4;
    const int nelem = N * 128;
    const unsigned short* embh = (const unsigned short*)emb;

    // sentinel stub (template symbol; d_out fully overwritten by layer 2)
    RGCNEncoder_89962384982025_kernel<<<1, 256, 0, stream>>>((unsigned*)d_out, 256);

    // emb -> bf16 (dtype flag derived inline)
    cvt_rg<<<(nelem + 255) / 256, 256, 0, stream>>>(emb, xin, nelem);

    // CSR by (node, relation); in-place hierarchical scan
    zero_rg<<<(n16 + 255) / 256, 256, 0, stream>>>(cnt, n16);
    count_rg<<<eblk, 256, 0, stream>>>(ei, et, cnt, E);
    scanA_rg<<<nsb, 256, 0, stream>>>(cnt, rowptr2, bsum, n16);
    scanB_rg<<<1, 256, 0, stream>>>(bsum, nsb);
    scanC_rg<<<nsb, 256, 0, stream>>>(rowptr2, bsum, n16);
    fill_rg<<<eblk, 256, 0, stream>>>(ei, et, rowptr2, cnt, pcols, E);

    // layer 1: aggregate xin -> Gall (basis space), fused GEMM -> bf16 xmid
    wall_rg<<<kSeg * 64, 256, 0, stream>>>(bases1, coef1, selfw1, embh, wallT, coefw);
    agg2_rg<<<ablk, 256, 0, stream>>>(rowptr2, pcols, xin, coefw, Gall, N);
    fusegemm_rg<<<mblk64, 256, 0, stream>>>(Gall, xin, wallT, bias1, g1, b1, embh,
                                            xmid, (float*)nullptr, 0, N);

    // layer 2: aggregate xmid -> Gall, fused GEMM -> fp32 d_out
    wall_rg<<<kSeg * 64, 256, 0, stream>>>(bases2, coef2, selfw2, embh, wallT, coefw);
    agg2_rg<<<ablk, 256, 0, stream>>>(rowptr2, pcols, xmid, coefw, Gall, N);
    fusegemm_rg<<<mblk64, 256, 0, stream>>>(Gall, xmid, wallT, bias2, g2, b2, embh,
                                            (unsigned short*)nullptr, (float*)d_out,
                                            1, N);
}

// Round 13
// 359.166 us; speedup vs baseline: 1.3434x; 1.3434x over previous
//
#include <hip/hip_runtime.h>
#include <hip/hip_bf16.h>

// RGCN 2-layer encoder. N=50000, R=16, B=8, Dim=128, E=625000.
// fp32 in/out (runtime-detected), bf16 MFMA internals.
//
// R27b (resubmit; R27 bench was an infra failure, container died):
// (a) fusegemm M=128 tile (512thr/8 waves, 16 cols/wave): halves
// wallT L2 re-read traffic (230->115MB) and doubles MFMA per barrier
// stall; LDS 64KB dbuf -> 2 blocks/CU, lb(512,4) caps 128 VGPR. R26's
// barrier-free direct-VGPR A-loads regressed 2x (16B/lane scatter) ->
// LDS staging retained exactly as verified in R25 (seg-major Gall,
// B-first vmcnt order, both-sides XOR swizzle). (b) dispatch diet:
// cvt+zero merged into prep_rg; both layers' wallT/coefw in ONE launch
// (wall2_rg) before the layer chain. 12 dispatches.
//
// Pipeline per layer: wallT[b][o][k]=bases[b]^T (slot8=selfw^T) + coefw fp32;
// agg2: wave-per-node CSR scan -> Gall[b][n][o] (basis space, 102MB);
// fusegemm: out[n][o] = [G(n) | x[n]] @ wallT (K=1152), epilogue LN+ReLU.

static constexpr int kDim = 128;
static constexpr int kRel = 16;
static constexpr int kBas = 8;
static constexpr int kSeg = kBas + 1;   // 8 bases + self

typedef __attribute__((ext_vector_type(8))) short bf16x8;
typedef __attribute__((ext_vector_type(4))) float f32x4;

static __device__ __forceinline__ float bf2f_rg(unsigned short h) {
    return __uint_as_float(((unsigned)h) << 16);
}
static __device__ __forceinline__ unsigned short f2bf_rg(float f) {
    unsigned u = __float_as_uint(f);
    u = u + 0x7fffu + ((u >> 16) & 1u);   // round-to-nearest-even
    return (unsigned short)(u >> 16);
}

static __device__ __forceinline__ void gload_lds16(const void* g, void* l) {
    __builtin_amdgcn_global_load_lds(
        (const __attribute__((address_space(1))) unsigned*)g,
        (__attribute__((address_space(3))) unsigned*)l, 16, 0, 0);
}

// dtype flag from emb's first 128 halves (call with one full wave, tid<64):
// any bf16-decoded exponent >= 0x86 (|v|>=128/inf/nan) => input is fp32
static __device__ __forceinline__ int flag_from(const unsigned short* x, int lane) {
    unsigned e0 = ((unsigned)x[lane] >> 7) & 0xFFu;
    unsigned e1 = ((unsigned)x[lane + 64] >> 7) & 0xFFu;
    int bad = (e0 >= 0x86u) || (e1 >= 0x86u);
    return (__ballot(bad) != 0ull) ? 1 : 0;
}

// template-named kernel: sentinel stub (d_out fully overwritten by pipeline)
__global__ void RGCNEncoder_89962384982025_kernel(unsigned* p, int n) {
    int i = blockIdx.x * 256 + threadIdx.x;
    if (i < n) p[i] = 0x3F803F80u;
}

// prep: emb -> bf16 xin (flag inline) AND zero cnt (merged launches)
__global__ void prep_rg(const void* xraw, unsigned short* xout, int nelem,
                        int* cnt, int n16) {
    __shared__ int fsh;
    if (threadIdx.x < 64) {
        int fl = flag_from((const unsigned short*)xraw, threadIdx.x);
        if (threadIdx.x == 0) fsh = fl;
    }
    __syncthreads();
    int f = fsh;
    int i = blockIdx.x * 256 + threadIdx.x;
    if (i < n16) cnt[i] = 0;
    if (i < nelem) {
        if (f)
            xout[i] = f2bf_rg(((const float*)xraw)[i]);
        else
            xout[i] = ((const unsigned short*)xraw)[i];
    }
}

__global__ void count_rg(const int* ei, const int* et, int* cnt, int E) {
    int e = blockIdx.x * 256 + threadIdx.x;
    if (e < E) atomicAdd(&cnt[ei[e] * kRel + et[e]], 1);
}

// hierarchical scan, in place on rowptr (saves the incl buffer)
__global__ void scanA_rg(const int* cnt, int* rowptr, int* bsum, int n) {
    __shared__ int sh[256];
    int tid = threadIdx.x;
    int i = blockIdx.x * 256 + tid;
    int v = (i < n) ? cnt[i] : 0;
    sh[tid] = v;
    __syncthreads();
    for (int off = 1; off < 256; off <<= 1) {
        int t = (tid >= off) ? sh[tid - off] : 0;
        __syncthreads();
        sh[tid] += t;
        __syncthreads();
    }
    if (i < n) rowptr[i + 1] = sh[tid];
    if (tid == 255) bsum[blockIdx.x] = sh[255];
}
__global__ void scanB_rg(int* bsum, int nb) {
    __shared__ int partial[256];
    int tid = threadIdx.x;
    int chunk = (nb + 255) / 256;
    int s0 = tid * chunk;
    int s1 = min(s0 + chunk, nb);
    int sum = 0;
    for (int i = s0; i < s1; ++i) sum += bsum[i];
    partial[tid] = sum;
    __syncthreads();
    for (int off = 1; off < 256; off <<= 1) {
        int t = (tid >= off) ? partial[tid - off] : 0;
        __syncthreads();
        partial[tid] += t;
        __syncthreads();
    }
    int run = (tid == 0) ? 0 : partial[tid - 1];
    for (int i = s0; i < s1; ++i) { int v = bsum[i]; bsum[i] = run; run += v; }
}
__global__ void scanC_rg(int* rowptr, const int* bsum, int n) {
    int i = blockIdx.x * 256 + threadIdx.x;
    if (i < n) rowptr[i + 1] += bsum[blockIdx.x];
    if (i == 0) rowptr[0] = 0;
}

// fill: pcols entry packs col | rel<<26 (col < 2^26)
__global__ void fill_rg(const int* ei, const int* et, const int* rowptr,
                        int* cnt, int* pcols, int E) {
    int e = blockIdx.x * 256 + threadIdx.x;
    if (e < E) {
        int rel = et[e];
        int key = ei[e] * kRel + rel;
        int old = atomicSub(&cnt[key], 1);
        pcols[rowptr[key] + old - 1] = ei[E + e] | (rel << 26);
    }
}

// BOTH layers in one launch: wallT[L][b][o][k] = bases_L[b][k][o] (b<8),
// slot 8 = selfw_L^T; coefw[L][16][8] decoded fp32.
__global__ void wall2_rg(const void* bases1, const void* coef1, const void* selfw1,
                         const void* bases2, const void* coef2, const void* selfw2,
                         const unsigned short* emb, unsigned short* wallT,
                         float* coefw) {
    __shared__ int fsh;
    if (threadIdx.x < 64) {
        int fl = flag_from(emb, threadIdx.x);
        if (threadIdx.x == 0) fsh = fl;
    }
    __syncthreads();
    int f = fsh;
    int bi = blockIdx.x;
    int layer = (bi >= kSeg * 64) ? 1 : 0;
    int lb = bi - layer * kSeg * 64;
    const void* bases = layer ? bases2 : bases1;
    const void* coef  = layer ? coef2  : coef1;
    const void* selfw = layer ? selfw2 : selfw1;
    int idx = lb * 256 + threadIdx.x;   // b*16384 + o*128 + k
    int b = idx >> 14;
    int o = (idx >> 7) & 127;
    int k = idx & 127;
    if (lb == 0 && threadIdx.x < kRel * kBas) {
        coefw[layer * 128 + threadIdx.x] =
            f ? ((const float*)coef)[threadIdx.x]
              : bf2f_rg(((const unsigned short*)coef)[threadIdx.x]);
    }
    unsigned short* wout = wallT + (size_t)layer * kSeg * 16384;
    if (b < kBas) {
        float bv = f ? ((const float*)bases)[b * 16384 + k * 128 + o]
                     : bf2f_rg(((const unsigned short*)bases)[b * 16384 + k * 128 + o]);
        wout[idx] = f2bf_rg(bv);
    } else {
        float sv = f ? ((const float*)selfw)[k * 128 + o]
                     : bf2f_rg(((const unsigned short*)selfw)[k * 128 + o]);
        wout[idx] = f2bf_rg(sv);
    }
}

// aggregate-first in basis space: Gall[b][n][o] = sum_r coefw[r][b] *
// mean over r-bucket edges of x[col][o]. Wave per node (4 waves/block).
// Depth-4 batched gather: 4 readlanes + 4 independent loads in flight,
// then bucket-transition logic on the returned values (latency overlap).
__global__ __launch_bounds__(256) void agg2_rg(const int* rowptr2, const int* pcols,
                                               const unsigned short* xsrc,
                                               const float* coefw,
                                               unsigned short* Gall, int N) {
    __shared__ float csh[kRel * kBas];
    if (threadIdx.x < kRel * kBas) csh[threadIdx.x] = coefw[threadIdx.x];
    __syncthreads();
    int wv = threadIdx.x >> 6;
    int lane = threadIdx.x & 63;
    int n = blockIdx.x * 4 + wv;
    if (n >= N) return;
    const int s = rowptr2[n * kRel];          // wave-uniform -> scalar load
    const int e = rowptr2[n * kRel + kRel];
    const unsigned short* xl = xsrc + 2 * lane;
    float g0[kBas], g1[kBas];
#pragma unroll
    for (int b = 0; b < kBas; ++b) { g0[b] = 0.f; g1[b] = 0.f; }
    float s0 = 0.f, s1 = 0.f;
    int cur = -1, cnt = 0;
    auto flush = [&]() {
        float w = __builtin_amdgcn_rcpf((float)cnt);
        float t0 = s0 * w, t1 = s1 * w;
        const float* cr = csh + cur * kBas;
#pragma unroll
        for (int b = 0; b < kBas; ++b) {
            float c = cr[b];                  // broadcast ds_read
            g0[b] += c * t0;
            g1[b] += c * t1;
        }
        s0 = 0.f; s1 = 0.f; cnt = 0;
    };
    for (int base = s; base < e; base += 64) {
        int m = e - base;
        if (m > 64) m = 64;
        int pk = 0;
        if (base + lane < e) pk = pcols[base + lane];
        int i = 0;
        for (; i + 4 <= m; i += 4) {
            // issue 4 independent gathers back-to-back (4 in flight)
            int v0 = __builtin_amdgcn_readlane(pk, i);
            int v1 = __builtin_amdgcn_readlane(pk, i + 1);
            int v2 = __builtin_amdgcn_readlane(pk, i + 2);
            int v3 = __builtin_amdgcn_readlane(pk, i + 3);
            unsigned u0 = *(const unsigned*)(xl + (size_t)(v0 & 0x03FFFFFF) * 128);
            unsigned u1 = *(const unsigned*)(xl + (size_t)(v1 & 0x03FFFFFF) * 128);
            unsigned u2 = *(const unsigned*)(xl + (size_t)(v2 & 0x03FFFFFF) * 128);
            unsigned u3 = *(const unsigned*)(xl + (size_t)(v3 & 0x03FFFFFF) * 128);
            int r0 = (int)((unsigned)v0 >> 26);
            int r1 = (int)((unsigned)v1 >> 26);
            int r2 = (int)((unsigned)v2 >> 26);
            int r3 = (int)((unsigned)v3 >> 26);
            if (r0 != cur) { if (cnt) flush(); cur = r0; }
            s0 += __uint_as_float(u0 << 16); s1 += __uint_as_float(u0 & 0xffff0000u); ++cnt;
            if (r1 != cur) { flush(); cur = r1; }
            s0 += __uint_as_float(u1 << 16); s1 += __uint_as_float(u1 & 0xffff0000u); ++cnt;
            if (r2 != cur) { flush(); cur = r2; }
            s0 += __uint_as_float(u2 << 16); s1 += __uint_as_float(u2 & 0xffff0000u); ++cnt;
            if (r3 != cur) { flush(); cur = r3; }
            s0 += __uint_as_float(u3 << 16); s1 += __uint_as_float(u3 & 0xffff0000u); ++cnt;
        }
        for (; i < m; ++i) {
            int v = __builtin_amdgcn_readlane(pk, i);
            unsigned u = *(const unsigned*)(xl + (size_t)(v & 0x03FFFFFF) * 128);
            int rel = (int)((unsigned)v >> 26);
            if (rel != cur) { if (cnt) flush(); cur = rel; }
            s0 += __uint_as_float(u << 16);
            s1 += __uint_as_float(u & 0xffff0000u);
            ++cnt;
        }
    }
    if (cnt) flush();
    unsigned short* grow = Gall + (size_t)n * 128 + 2 * lane;
    const size_t plane = (size_t)N * 128;
#pragma unroll
    for (int b = 0; b < kBas; ++b) {
        unsigned outp = (unsigned)f2bf_rg(g0[b]) | ((unsigned)f2bf_rg(g1[b]) << 16);
        *(unsigned*)(grow + (size_t)b * plane) = outp;
    }
}

// fused GEMM: out[n][o] = [G(n) (K=1024) | x[n] (K=128)] @ wallT[seg][o][k]
// + bias, then LayerNorm + ReLU in-epilogue. 128-row C-tile, 512 threads
// (8 waves), each wave owns 128 rows x 16 cols (col = wave*16 + lane&15).
// 16x16x32 bf16 MFMA; C map m89/m91: col=lane&15, row=(lane>>4)*4+reg.
// Double-buffered global_load_lds A-tile (64KB) with row-XOR swizzle
// (both-sides); per segment: B-loads FIRST (oldest in vmcnt queue), then
// stage(seg+1), then ds_read+MFMA, then vmcnt(0)+barrier. Segment-major
// Gall: each stage reads a contiguous 32KB run.
__global__ __launch_bounds__(512, 4) void fusegemm_rg(const unsigned short* Gall,
                                                      const unsigned short* x,
                                                      const unsigned short* wallT,
                                                      const void* bias, const void* gw,
                                                      const void* bw,
                                                      const unsigned short* emb,
                                                      unsigned short* out_b, float* out_f,
                                                      int ofp32, int M) {
    __shared__ __align__(16) unsigned short As[2][128][128];   // 64KB, swizzled
    __shared__ float pS[128][8];
    __shared__ float pQ[128][8];
    __shared__ float mrs[128][2];
    __shared__ int fsh;
    const int m0 = blockIdx.x * 128;
    const int tid = threadIdx.x;
    const int wave = tid >> 6;
    const int lane = tid & 63;
    const int wn = wave * 16;            // 16 cols per wave
    const int lrow = lane & 15;
    const int lq = lane >> 4;
    if (tid < 64) {
        int fl = flag_from(emb, tid);
        if (tid == 0) fsh = fl;
    }

    // stage segment seg into As[buf]: 4 x global_load_lds(16B) per thread.
    // granule gi=it*512+tid: row=gi>>4, slot=gi&15, linear LDS dest;
    // source within-row byte = slot*16 ^ ((row&7)<<4)  (pre-swizzle, #21).
    auto stage = [&](int seg, int buf) {
        const char* srcb = (seg < kBas)
            ? (const char*)(Gall + (size_t)seg * (size_t)M * 128)
            : (const char*)x;
#pragma unroll
        for (int it = 0; it < 4; ++it) {
            int gi = it * 512 + tid;
            int row = gi >> 4;
            int c = ((gi & 15) << 4) ^ ((row & 7) << 4);
            int gr = m0 + row;
            if (gr > M - 1) gr = M - 1;
            const char* src = srcb + (size_t)gr * 256 + (size_t)c;
            unsigned short* ldst = &As[buf][0][0] + gi * 8;
            gload_lds16(src, ldst);
        }
    };

    f32x4 acc[8] = {};
    // prologue: stage segment 0, drain + publish fsh
    stage(0, 0);
    __syncthreads();
    int cur = 0;
    for (int seg = 0; seg < kSeg; ++seg) {
        // B-loads FIRST (oldest in vmcnt queue -> their wait doesn't drain stage)
        const unsigned short* Bsrc = wallT + (size_t)seg * 16384
                                   + (size_t)(wn + lrow) * 128;
        bf16x8 b[4];
#pragma unroll
        for (int kk4 = 0; kk4 < 4; ++kk4)
            b[kk4] = *(const bf16x8*)(Bsrc + kk4 * 32 + lq * 8);
        __builtin_amdgcn_sched_barrier(0);   // pin: b-loads issue before stage
        if (seg < kSeg - 1) stage(seg + 1, cur ^ 1);
#pragma unroll
        for (int kk4 = 0; kk4 < 4; ++kk4) {
#pragma unroll
            for (int mt = 0; mt < 8; ++mt) {
                int row = mt * 16 + lrow;
                int cb = (kk4 * 64 + lq * 16) ^ ((row & 7) << 4);
                bf16x8 a = *(const bf16x8*)((const char*)&As[cur][0][0]
                                            + row * 256 + cb);
                acc[mt] = __builtin_amdgcn_mfma_f32_16x16x32_bf16(
                    a, b[kk4], acc[mt], 0, 0, 0);
            }
        }
        asm volatile("s_waitcnt vmcnt(0)" ::: "memory");
        __builtin_amdgcn_s_barrier();
        cur ^= 1;
    }

    // epilogue: +bias, row mean/var across 128 cols (8 waves x 16 cols), LN+ReLU
    const int f = fsh;
    const int gc = wn + lrow;
    float bv, gv, betav;
    if (f) {
        bv = ((const float*)bias)[gc];
        gv = ((const float*)gw)[gc];
        betav = ((const float*)bw)[gc];
    } else {
        bv = bf2f_rg(((const unsigned short*)bias)[gc]);
        gv = bf2f_rg(((const unsigned short*)gw)[gc]);
        betav = bf2f_rg(((const unsigned short*)bw)[gc]);
    }
#pragma unroll
    for (int mt = 0; mt < 8; ++mt)
#pragma unroll
        for (int i = 0; i < 4; ++i) {
            float v = acc[mt][i] + bv;
            acc[mt][i] = v;
            float sv = v, qv = v * v;
            for (int o = 1; o < 16; o <<= 1) {
                sv += __shfl_xor(sv, o);
                qv += __shfl_xor(qv, o);
            }
            if (lrow == 0) {
                int row = mt * 16 + lq * 4 + i;
                pS[row][wave] = sv;
                pQ[row][wave] = qv;
            }
        }
    __syncthreads();
    if (tid < 128) {
        float s8 = 0.f, q8 = 0.f;
#pragma unroll
        for (int w = 0; w < 8; ++w) { s8 += pS[tid][w]; q8 += pQ[tid][w]; }
        float mean = s8 * (1.0f / 128.0f);
        float var = q8 * (1.0f / 128.0f) - mean * mean;
        mrs[tid][0] = mean;
        mrs[tid][1] = rsqrtf(var + 1e-5f);
    }
    __syncthreads();
#pragma unroll
    for (int mt = 0; mt < 8; ++mt)
#pragma unroll
        for (int i = 0; i < 4; ++i) {
            int row = mt * 16 + lq * 4 + i;
            int gr = m0 + row;
            if (gr < M) {
                float o = fmaxf((acc[mt][i] - mrs[row][0]) * mrs[row][1] * gv + betav,
                                0.f);
                if (ofp32)
                    out_f[(size_t)gr * 128 + gc] = o;
                else
                    out_b[(size_t)gr * 128 + gc] = f2bf_rg(o);
            }
        }
}

extern "C" void kernel_launch(void* const* d_in, const int* in_sizes, int n_in,
                              void* d_out, int out_size, void* d_ws, size_t ws_size,
                              hipStream_t stream) {
    const int* ei = (const int*)d_in[0];            // [2,E] int32
    const int* et = (const int*)d_in[1];            // [E] int32
    const void* emb    = d_in[2];
    const void* bases1 = d_in[3];
    const void* coef1  = d_in[4];
    const void* selfw1 = d_in[5];
    const void* bias1  = d_in[6];
    const void* g1     = d_in[7];
    const void* b1     = d_in[8];
    const void* bases2 = d_in[9];
    const void* coef2  = d_in[10];
    const void* selfw2 = d_in[11];
    const void* bias2  = d_in[12];
    const void* g2     = d_in[13];
    const void* b2     = d_in[14];

    const int E = in_sizes[1];
    const int N = out_size / kDim;
    const int n16 = N * kRel;
    const int nsb = (n16 + 255) / 256;

    // workspace (256B-aligned). Gall = [8][N][128] bf16 (102.4MB, seg-major).
    char* ws = (char*)d_ws;
    size_t off = 0;
    float* coefw = (float*)(ws + off); off += 1024;                 // 2 layers
    int* rowptr2 = (int*)(ws + off); off += (((size_t)n16 + 1) * 4 + 255) & ~(size_t)255;
    int* cnt     = (int*)(ws + off); off += ((size_t)n16 * 4 + 255) & ~(size_t)255;
    int* bsum    = (int*)(ws + off); off += ((size_t)nsb * 4 + 255) & ~(size_t)255;
    int* pcols   = (int*)(ws + off); off += ((size_t)E * 4 + 255) & ~(size_t)255;
    unsigned short* wallT = (unsigned short*)(ws + off);            // 2 layers
    off += ((size_t)2 * kSeg * 16384 * 2 + 255) & ~(size_t)255;
    unsigned short* xin  = (unsigned short*)(ws + off);
    off += ((size_t)N * 128 * 2 + 255) & ~(size_t)255;
    unsigned short* xmid = (unsigned short*)(ws + off);
    off += ((size_t)N * 128 * 2 + 255) & ~(size_t)255;
    unsigned short* Gall = (unsigned short*)(ws + off);
    (void)n_in; (void)ws_size;

    const int eblk = (E + 255) / 256;
    const int mblk128 = (N + 127) / 128;
    const int ablk = (N + 3) / 4;
    const int nelem = N * 128;
    const unsigned short* embh = (const unsigned short*)emb;

    // sentinel stub (template symbol; d_out fully overwritten by layer 2)
    RGCNEncoder_89962384982025_kernel<<<1, 256, 0, stream>>>((unsigned*)d_out, 256);

    // prep: emb -> bf16 xin + zero cnt (one launch)
    prep_rg<<<(nelem + 255) / 256, 256, 0, stream>>>(emb, xin, nelem, cnt, n16);

    // CSR by (node, relation); in-place hierarchical scan
    count_rg<<<eblk, 256, 0, stream>>>(ei, et, cnt, E);
    scanA_rg<<<nsb, 256, 0, stream>>>(cnt, rowptr2, bsum, n16);
    scanB_rg<<<1, 256, 0, stream>>>(bsum, nsb);
    scanC_rg<<<nsb, 256, 0, stream>>>(rowptr2, bsum, n16);
    fill_rg<<<eblk, 256, 0, stream>>>(ei, et, rowptr2, cnt, pcols, E);

    // both layers' weights upfront (one launch)
    wall2_rg<<<2 * kSeg * 64, 256, 0, stream>>>(bases1, coef1, selfw1,
                                                bases2, coef2, selfw2,
                                                embh, wallT, coefw);

    // layer 1: aggregate xin -> Gall (basis space), fused GEMM -> bf16 xmid
    agg2_rg<<<ablk, 256, 0, stream>>>(rowptr2, pcols, xin, coefw, Gall, N);
    fusegemm_rg<<<mblk128, 512, 0, stream>>>(Gall, xin, wallT, bias1, g1, b1, embh,
                                             xmid, (float*)nullptr, 0, N);

    // layer 2: aggregate xmid -> Gall, fused GEMM -> fp32 d_out
    agg2_rg<<<ablk, 256, 0, stream>>>(rowptr2, pcols, xmid, coefw + 128, Gall, N);
    fusegemm_rg<<<mblk128, 512, 0, stream>>>(Gall, xmid, wallT + (size_t)kSeg * 16384,
                                             bias2, g2, b2, embh,
                                             (unsigned short*)nullptr, (float*)d_out,
                                             1, N);
}